// Round 6
// baseline (3198.549 us; speedup 1.0000x reference)
//
#include <hip/hip_runtime.h>
#include <math.h>

#define Bq 16
#define Hc 384
#define Tt 2048
#define N2 32
#define LYR 6
#define HFq 1536
#define TWOH 768
#define CHUNK 128
#define NCH (Tt/CHUNK)   // 16
#define BC (Bq*NCH)      // 256 chunk instances

typedef __bf16 bf16x8 __attribute__((ext_vector_type(8)));
typedef float floatx4 __attribute__((ext_vector_type(4)));

__device__ __forceinline__ unsigned short bfbits(float f) {
  union { float f; unsigned u; } x; x.f = f;
  return (unsigned short)((x.u + 0x7FFF + ((x.u >> 16) & 1)) >> 16);
}

// ---------------- param precompute (fp64 for accuracy) ----------------
// cdre/cdim hold 2*Cd (factor 2 folded).
__global__ void param_kernel(const float* __restrict__ log_dt,
                             const float* __restrict__ A_re, const float* __restrict__ A_im,
                             const float* __restrict__ C_re, const float* __restrict__ C_im,
                             float* __restrict__ wre, float* __restrict__ wim,
                             float* __restrict__ cdre, float* __restrict__ cdim,
                             float* __restrict__ wSre, float* __restrict__ wSim) {
  int idx = blockIdx.x * blockDim.x + threadIdx.x;
  if (idx >= LYR * Hc * N2) return;
  int hn = idx / N2;
  double dt = exp((double)log_dt[hn]);
  double are = (double)A_re[idx], aim = (double)A_im[idx];
  double dre = are * dt, dimv = aim * dt;
  double er = exp(dre);
  double wr = er * cos(dimv), wi_ = er * sin(dimv);
  double den = are * are + aim * aim;
  double nr = wr - 1.0, ni = wi_;
  double qr = (nr * are + ni * aim) / den;
  double qi = (ni * are - nr * aim) / den;
  double cr = (double)C_re[idx], ci = (double)C_im[idx];
  cdre[idx] = (float)(2.0 * (cr * qr - ci * qi));
  cdim[idx] = (float)(2.0 * (cr * qi + ci * qr));
  wre[idx] = (float)wr; wim[idx] = (float)wi_;
  double es = exp(dre * (double)CHUNK);
  wSre[idx] = (float)(es * cos(dimv * (double)CHUNK));
  wSim[idx] = (float)(es * sin(dimv * (double)CHUNK));
}

// ---------------- weight fp32 -> bf16 (RNE) ----------------
__global__ void cvt_bf16_kernel(const float* __restrict__ in, unsigned short* __restrict__ out,
                                int n4) {
  int idx = blockIdx.x * 256 + threadIdx.x;
  if (idx >= n4) return;
  float4 v = ((const float4*)in)[idx];
  ushort4 o;
  o.x = bfbits(v.x); o.y = bfbits(v.y); o.z = bfbits(v.z); o.w = bfbits(v.w);
  ((ushort4*)out)[idx] = o;
}

// ---------------- transpose (B,C,T) -> (B,T,C) ----------------
__global__ __launch_bounds__(256) void transpose_fwd(const float* __restrict__ in,
                                                     float* __restrict__ out) {
  __shared__ float tile[32][33];
  int tx = threadIdx.x, ty = threadIdx.y;
  int t0 = blockIdx.x * 32, c0 = blockIdx.y * 32, b = blockIdx.z;
#pragma unroll
  for (int k = 0; k < 4; k++)
    tile[ty + 8 * k][tx] = in[((size_t)(b * Hc + c0 + ty + 8 * k)) * Tt + t0 + tx];
  __syncthreads();
#pragma unroll
  for (int k = 0; k < 4; k++)
    out[((size_t)(b * Tt + t0 + ty + 8 * k)) * Hc + c0 + tx] = tile[tx][ty + 8 * k];
}

// ---------------- transpose (B,T,C) -> (B,C,T) with mask ----------------
__global__ __launch_bounds__(256) void transpose_bwd(const float* __restrict__ in,
                                                     const float* __restrict__ mask,
                                                     float* __restrict__ out) {
  __shared__ float tile[32][33];
  int tx = threadIdx.x, ty = threadIdx.y;
  int t0 = blockIdx.x * 32, c0 = blockIdx.y * 32, b = blockIdx.z;
#pragma unroll
  for (int k = 0; k < 4; k++)
    tile[ty + 8 * k][tx] = in[((size_t)(b * Tt + t0 + ty + 8 * k)) * Hc + c0 + tx];
  __syncthreads();
  float mv = mask[(size_t)b * Tt + t0 + tx];
#pragma unroll
  for (int k = 0; k < 4; k++)
    out[((size_t)(b * Hc + c0 + ty + 8 * k)) * Tt + t0 + tx] = tile[tx][ty + 8 * k] * mv;
}

// ---------------- fill Toeplitz conv table T'[h][t][tau] = k[t-tau] (+D on diag) ----------------
// block per h; thread = (t, half); each half handles 16 modes, combined via shfl.
__global__ __launch_bounds__(256) void fillT_k(
    const float* __restrict__ wre, const float* __restrict__ wim,
    const float* __restrict__ cdre, const float* __restrict__ cdim,
    const float* __restrict__ Dv, unsigned short* __restrict__ Ttab) {
  int h = blockIdx.x;
  int t = threadIdx.x >> 1, half = threadIdx.x & 1;
  int nb = half * 16;
  float wr[16], wi[16], cdr[16], cdi[16], pr[16], pi[16];
#pragma unroll
  for (int n = 0; n < 16; n++) {
    wr[n] = wre[h * N2 + nb + n]; wi[n] = wim[h * N2 + nb + n];
    cdr[n] = cdre[h * N2 + nb + n]; cdi[n] = cdim[h * N2 + nb + n];
    pr[n] = 1.f; pi[n] = 0.f;
  }
  float d = Dv[h];
  unsigned short* Trow = Ttab + ((size_t)h * CHUNK + t) * CHUNK;
  for (int dlt = 0; dlt <= t; dlt++) {
    float part = 0.f;
#pragma unroll
    for (int n = 0; n < 16; n++) part += cdr[n] * pr[n] - cdi[n] * pi[n];
    float tot = part + __shfl_xor(part, 1);
    if (dlt == 0) tot += d;
    if ((dlt & 1) == half) Trow[t - dlt] = bfbits(tot);
#pragma unroll
    for (int n = 0; n < 16; n++) {
      float p0 = pr[n];
      pr[n] = p0 * wr[n] - pi[n] * wi[n];
      pi[n] = p0 * wi[n] + pi[n] * wr[n];
    }
  }
  for (int tau = t + 1; tau < CHUNK; tau++)
    if ((tau & 1) == half) Trow[tau] = 0;
}

// ---------------- fill correction table M[h][t][2n]=Re(2Cd w^{t+1}), [2n+1]=-Im ----------------
__global__ void fillM_k(const float* __restrict__ wre, const float* __restrict__ wim,
                        const float* __restrict__ cdre, const float* __restrict__ cdim,
                        unsigned short* __restrict__ Mtab) {
  int idx = blockIdx.x * 256 + threadIdx.x;  // 384*128
  if (idx >= Hc * CHUNK) return;
  int t = idx & (CHUNK - 1), h = idx >> 7;
  unsigned short* Mrow = Mtab + ((size_t)h * CHUNK + t) * (2 * N2);
  for (int n = 0; n < N2; n++) {
    float wr = wre[h * N2 + n], wi = wim[h * N2 + n];
    float cr = cdre[h * N2 + n], ci = cdim[h * N2 + n];
    float prr = wr, pii = wi;  // w^{t+1}
    for (int s = 0; s < t; s++) {
      float p0 = prr; prr = p0 * wr - pii * wi; pii = p0 * wi + pii * wr;
    }
    float mre = cr * prr - ci * pii;
    float mim = cr * pii + ci * prr;
    Mrow[2 * n] = bfbits(mre);
    Mrow[2 * n + 1] = bfbits(-mim);
  }
}

// ---------------- fill state-gather table E[h][2n][tau]=Re(w^{127-tau}), [2n+1]=Im ----------------
__global__ void fillE_k(const float* __restrict__ wre, const float* __restrict__ wim,
                        unsigned short* __restrict__ Etab) {
  int idx = blockIdx.x * 256 + threadIdx.x;  // 384*32
  if (idx >= Hc * N2) return;
  int n = idx & (N2 - 1), h = idx >> 5;
  float wr = wre[h * N2 + n], wi = wim[h * N2 + n];
  float pr = 1.f, pi = 0.f;
  unsigned short* E0 = Etab + ((size_t)h * (2 * N2) + 2 * n) * CHUNK;
  unsigned short* E1 = E0 + CHUNK;
  for (int tau = CHUNK - 1; tau >= 0; tau--) {
    E0[tau] = bfbits(pr); E1[tau] = bfbits(pi);
    float p0 = pr; pr = p0 * wr - pi * wi; pi = p0 * wi + pi * wr;
  }
}

// ---------------- xprep: xT (B,T,C) fp32 -> Xbf[h][bc][tau] bf16 (masked) ----------------
__global__ __launch_bounds__(256) void xprep_k(const float* __restrict__ xT,
                                               const float* __restrict__ mask,
                                               unsigned short* __restrict__ Xbf) {
  __shared__ float tile[32][33];
  int tx = threadIdx.x, ty = threadIdx.y;
  int t0 = blockIdx.x * 32, c0 = blockIdx.y * 32, b = blockIdx.z;
#pragma unroll
  for (int k = 0; k < 4; k++) {
    int t = t0 + ty + 8 * k;
    tile[ty + 8 * k][tx] = xT[((size_t)(b * Tt + t)) * Hc + c0 + tx] * mask[(size_t)b * Tt + t];
  }
  __syncthreads();
#pragma unroll
  for (int k = 0; k < 4; k++) {
    int h = c0 + ty + 8 * k;
    int tg = t0 + tx;
    Xbf[((size_t)h * BC + b * NCH + (tg >> 7)) * CHUNK + (tg & (CHUNK - 1))] =
        bfbits(tile[tx][ty + 8 * k]);
  }
}

// ---------------- states GEMM: S_raw[h][bc][k64] = E[h] (64x128) * X[h] (128xBC) ----------------
__global__ __launch_bounds__(256) void states_gemm(
    const __bf16* __restrict__ Etab, const __bf16* __restrict__ Xbf,
    float* __restrict__ Sraw) {
  __shared__ __bf16 As[64][32];
  __shared__ __bf16 Bs[128][32];
  int tid = threadIdx.x;
  int h = blockIdx.y, n0 = blockIdx.x * 128;
  int wave = tid >> 6, lane = tid & 63, l16 = lane & 15, quad = lane >> 4;
  int sr = tid >> 2, sk = (tid & 3) * 8;
  floatx4 acc[8];
#pragma unroll
  for (int j = 0; j < 8; j++) acc[j] = (floatx4){0.f, 0.f, 0.f, 0.f};
  const __bf16* Eh = Etab + (size_t)h * 64 * CHUNK;
  const __bf16* Xh = Xbf + (size_t)h * BC * CHUNK;
  for (int k0 = 0; k0 < CHUNK; k0 += 32) {
    uint4 a0 = *(const uint4*)(Eh + (size_t)sr * CHUNK + k0 + sk);
    uint4 b0 = *(const uint4*)(Xh + (size_t)(n0 + sr) * CHUNK + k0 + sk);
    uint4 b1 = *(const uint4*)(Xh + (size_t)(n0 + sr + 64) * CHUNK + k0 + sk);
    __syncthreads();
    *(uint4*)&As[sr][sk] = a0;
    *(uint4*)&Bs[sr][sk] = b0; *(uint4*)&Bs[sr + 64][sk] = b1;
    __syncthreads();
    bf16x8 af = *(const bf16x8*)&As[wave * 16 + l16][quad * 8];
#pragma unroll
    for (int j = 0; j < 8; j++) {
      bf16x8 bf = *(const bf16x8*)&Bs[j * 16 + l16][quad * 8];
      acc[j] = __builtin_amdgcn_mfma_f32_16x16x32_bf16(af, bf, acc[j], 0, 0, 0);
    }
  }
#pragma unroll
  for (int j = 0; j < 8; j++) {
    int col = n0 + j * 16 + l16;
#pragma unroll
    for (int r = 0; r < 4; r++) {
      int row = wave * 16 + quad * 4 + r;
      Sraw[((size_t)h * BC + col) * 64 + row] = acc[j][r];
    }
  }
}

// ---------------- prefix over chunks (fp32), emit bf16 incoming states ----------------
__global__ void prefix_k(const float* __restrict__ Sraw, unsigned short* __restrict__ Sbf,
                         const float* __restrict__ wSre, const float* __restrict__ wSim) {
  int idx = blockIdx.x * 256 + threadIdx.x;  // 384*16*32
  if (idx >= Hc * Bq * N2) return;
  int n = idx & (N2 - 1);
  int b = (idx >> 5) & (Bq - 1);
  int h = idx >> 9;
  float wr = wSre[h * N2 + n], wi = wSim[h * N2 + n];
  float cr = 0.f, ci = 0.f;
  for (int c = 0; c < NCH; c++) {
    size_t off = ((size_t)h * BC + b * NCH + c) * 64 + 2 * n;
    float2 s = *(const float2*)(Sraw + off);
    Sbf[off] = bfbits(cr); Sbf[off + 1] = bfbits(ci);
    float c0 = cr;
    cr = fmaf(wr, c0, fmaf(-wi, ci, s.x));
    ci = fmaf(wr, ci, fmaf(wi, c0, s.y));
  }
}

// ---------------- conv GEMM: Y[h][t][bc] = gelu( [T'|M][h] (128x192) * [X;S][h] (192xBC) ) ----------------
__global__ __launch_bounds__(256) void conv_gemm(
    const __bf16* __restrict__ Ttab, const __bf16* __restrict__ Mtab,
    const __bf16* __restrict__ Xbf, const __bf16* __restrict__ Sbf,
    unsigned short* __restrict__ Yh) {
  __shared__ __bf16 As[128][32];
  __shared__ __bf16 Bs[128][32];
  int tid = threadIdx.x;
  int h = blockIdx.y, n0 = blockIdx.x * 128;
  int wave = tid >> 6, lane = tid & 63, l16 = lane & 15, quad = lane >> 4;
  int wm = wave >> 1, wn = wave & 1;
  int sr = tid >> 2, sk = (tid & 3) * 8;
  floatx4 acc[4][4];
#pragma unroll
  for (int i = 0; i < 4; i++)
#pragma unroll
    for (int j = 0; j < 4; j++) acc[i][j] = (floatx4){0.f, 0.f, 0.f, 0.f};
  const __bf16* Th = Ttab + (size_t)h * CHUNK * CHUNK;
  const __bf16* Mh = Mtab + (size_t)h * CHUNK * 64;
  const __bf16* Xh = Xbf + (size_t)h * BC * CHUNK;
  const __bf16* Sh = Sbf + (size_t)h * BC * 64;
  // phase 1: K = 128 (T' x X)
  for (int k0 = 0; k0 < CHUNK; k0 += 32) {
    uint4 a0 = *(const uint4*)(Th + (size_t)sr * CHUNK + k0 + sk);
    uint4 a1 = *(const uint4*)(Th + (size_t)(sr + 64) * CHUNK + k0 + sk);
    uint4 b0 = *(const uint4*)(Xh + (size_t)(n0 + sr) * CHUNK + k0 + sk);
    uint4 b1 = *(const uint4*)(Xh + (size_t)(n0 + sr + 64) * CHUNK + k0 + sk);
    __syncthreads();
    *(uint4*)&As[sr][sk] = a0; *(uint4*)&As[sr + 64][sk] = a1;
    *(uint4*)&Bs[sr][sk] = b0; *(uint4*)&Bs[sr + 64][sk] = b1;
    __syncthreads();
    bf16x8 af[4], bfr[4];
#pragma unroll
    for (int i = 0; i < 4; i++) af[i] = *(const bf16x8*)&As[wm * 64 + i * 16 + l16][quad * 8];
#pragma unroll
    for (int j = 0; j < 4; j++) bfr[j] = *(const bf16x8*)&Bs[wn * 64 + j * 16 + l16][quad * 8];
#pragma unroll
    for (int i = 0; i < 4; i++)
#pragma unroll
      for (int j = 0; j < 4; j++)
        acc[i][j] = __builtin_amdgcn_mfma_f32_16x16x32_bf16(af[i], bfr[j], acc[i][j], 0, 0, 0);
  }
  // phase 2: K = 64 (M x S)
  for (int k0 = 0; k0 < 64; k0 += 32) {
    uint4 a0 = *(const uint4*)(Mh + (size_t)sr * 64 + k0 + sk);
    uint4 a1 = *(const uint4*)(Mh + (size_t)(sr + 64) * 64 + k0 + sk);
    uint4 b0 = *(const uint4*)(Sh + (size_t)(n0 + sr) * 64 + k0 + sk);
    uint4 b1 = *(const uint4*)(Sh + (size_t)(n0 + sr + 64) * 64 + k0 + sk);
    __syncthreads();
    *(uint4*)&As[sr][sk] = a0; *(uint4*)&As[sr + 64][sk] = a1;
    *(uint4*)&Bs[sr][sk] = b0; *(uint4*)&Bs[sr + 64][sk] = b1;
    __syncthreads();
    bf16x8 af[4], bfr[4];
#pragma unroll
    for (int i = 0; i < 4; i++) af[i] = *(const bf16x8*)&As[wm * 64 + i * 16 + l16][quad * 8];
#pragma unroll
    for (int j = 0; j < 4; j++) bfr[j] = *(const bf16x8*)&Bs[wn * 64 + j * 16 + l16][quad * 8];
#pragma unroll
    for (int i = 0; i < 4; i++)
#pragma unroll
      for (int j = 0; j < 4; j++)
        acc[i][j] = __builtin_amdgcn_mfma_f32_16x16x32_bf16(af[i], bfr[j], acc[i][j], 0, 0, 0);
  }
  // epilogue: exact GELU, write Yh[h][t][bc]
#pragma unroll
  for (int i = 0; i < 4; i++) {
#pragma unroll
    for (int j = 0; j < 4; j++) {
      int col = n0 + wn * 64 + j * 16 + l16;
#pragma unroll
      for (int r = 0; r < 4; r++) {
        int t = wm * 64 + i * 16 + quad * 4 + r;
        float v = acc[i][j][r];
        v = 0.5f * v * (1.0f + erff(v * 0.70710678118654752f));
        Yh[((size_t)h * CHUNK + t) * BC + col] = bfbits(v);
      }
    }
  }
}

// ---------------- ytr: Yh[h][t][bc] -> ybf (B,T,C) ----------------
__global__ __launch_bounds__(256) void ytr_k(const unsigned short* __restrict__ Yh,
                                             unsigned short* __restrict__ ybf) {
  __shared__ unsigned short tile[32][33];
  int t = blockIdx.x;
  int bc0 = blockIdx.y * 32, h0 = blockIdx.z * 32;
  int tx = threadIdx.x, ty = threadIdx.y;
#pragma unroll
  for (int k = 0; k < 4; k++) {
    int h = h0 + ty + 8 * k;
    tile[ty + 8 * k][tx] = Yh[((size_t)h * CHUNK + t) * BC + bc0 + tx];
  }
  __syncthreads();
#pragma unroll
  for (int k = 0; k < 4; k++) {
    int bc = bc0 + ty + 8 * k;
    int b = bc >> 4, c = bc & (NCH - 1);
    ybf[((size_t)(b * Tt + c * CHUNK + t)) * Hc + h0 + tx] = tile[tx][ty + 8 * k];
  }
}

// ---------------- MFMA GEMM: out(B,T,N) = act(B,T,K) x W(N,K)^T ----------------
template <int EPI>
__global__ __launch_bounds__(256) void mfma_gemm(
    const __bf16* __restrict__ act, const __bf16* __restrict__ W,
    const float* __restrict__ bias, const float* __restrict__ mask,
    float* __restrict__ outf, unsigned short* __restrict__ outb,
    int K, int NOUT) {
  __shared__ __bf16 As[128][32];
  __shared__ __bf16 Bs[128][32];
  __shared__ __bf16 Bs2[(EPI == 2) ? 128 : 1][32];
  int tid = threadIdx.x;
  int b = blockIdx.z;
  int t0 = blockIdx.x * 128, n0 = blockIdx.y * 128;
  int wave = tid >> 6, lane = tid & 63, l16 = lane & 15, quad = lane >> 4;
  int wm = wave >> 1, wn = wave & 1;
  int sr = tid >> 2, sk = (tid & 3) * 8;

  floatx4 acc[4][4];
  floatx4 accg[(EPI == 2) ? 4 : 1][4];
#pragma unroll
  for (int i = 0; i < 4; i++)
#pragma unroll
    for (int j = 0; j < 4; j++) {
      acc[i][j] = (floatx4){0.f, 0.f, 0.f, 0.f};
      if constexpr (EPI == 2) accg[i][j] = (floatx4){0.f, 0.f, 0.f, 0.f};
    }

  const __bf16* aPtr = act + ((size_t)(b * Tt + t0 + sr)) * K + sk;
  const __bf16* bPtr = W + (size_t)(n0 + sr) * K + sk;
  const __bf16* gPtr = (EPI == 2) ? (W + (size_t)(NOUT + n0 + sr) * K + sk) : bPtr;

  for (int k0 = 0; k0 < K; k0 += 32) {
    uint4 a0 = *(const uint4*)(aPtr + k0);
    uint4 a1 = *(const uint4*)(aPtr + k0 + (size_t)64 * K);
    uint4 w0 = *(const uint4*)(bPtr + k0);
    uint4 w1 = *(const uint4*)(bPtr + k0 + (size_t)64 * K);
    uint4 g0, g1;
    if constexpr (EPI == 2) {
      g0 = *(const uint4*)(gPtr + k0);
      g1 = *(const uint4*)(gPtr + k0 + (size_t)64 * K);
    }
    __syncthreads();
    *(uint4*)&As[sr][sk] = a0; *(uint4*)&As[sr + 64][sk] = a1;
    *(uint4*)&Bs[sr][sk] = w0; *(uint4*)&Bs[sr + 64][sk] = w1;
    if constexpr (EPI == 2) { *(uint4*)&Bs2[sr][sk] = g0; *(uint4*)&Bs2[sr + 64][sk] = g1; }
    __syncthreads();
    bf16x8 af[4], bfr[4], gfr[(EPI == 2) ? 4 : 1];
#pragma unroll
    for (int i = 0; i < 4; i++)
      af[i] = *(const bf16x8*)&As[wm * 64 + i * 16 + l16][quad * 8];
#pragma unroll
    for (int j = 0; j < 4; j++) {
      bfr[j] = *(const bf16x8*)&Bs[wn * 64 + j * 16 + l16][quad * 8];
      if constexpr (EPI == 2)
        gfr[j] = *(const bf16x8*)&Bs2[wn * 64 + j * 16 + l16][quad * 8];
    }
#pragma unroll
    for (int i = 0; i < 4; i++)
#pragma unroll
      for (int j = 0; j < 4; j++) {
        acc[i][j] = __builtin_amdgcn_mfma_f32_16x16x32_bf16(af[i], bfr[j], acc[i][j], 0, 0, 0);
        if constexpr (EPI == 2)
          accg[i][j] = __builtin_amdgcn_mfma_f32_16x16x32_bf16(af[i], gfr[j], accg[i][j], 0, 0, 0);
      }
  }

#pragma unroll
  for (int i = 0; i < 4; i++) {
    int tb = t0 + wm * 64 + i * 16 + quad * 4;
    float mv[4];
    if constexpr (EPI == 1) {
#pragma unroll
      for (int r = 0; r < 4; r++) mv[r] = mask[(size_t)b * Tt + tb + r];
    }
#pragma unroll
    for (int j = 0; j < 4; j++) {
      int n = n0 + wn * 64 + j * 16 + l16;
      float bn = bias[n];
      float bg = (EPI == 2) ? bias[NOUT + n] : 0.f;
#pragma unroll
      for (int r = 0; r < 4; r++) {
        size_t o = ((size_t)(b * Tt + tb + r)) * NOUT + n;
        if constexpr (EPI == 0) {
          outf[o] = acc[i][j][r] + bn;
        } else if constexpr (EPI == 1) {
          float v = fmaxf(acc[i][j][r] + bn, 0.f) * mv[r];
          outb[o] = bfbits(v);
        } else {
          float a = acc[i][j][r] + bn;
          float g = accg[i][j][r] + bg;
          outf[o] = a / (1.f + expf(-g));
        }
      }
    }
  }
}

// ---------------- LayerNorm over C (contiguous), wave per row ----------------
__global__ __launch_bounds__(256) void ln_t(
    const float* __restrict__ in1, const float* __restrict__ in2,
    const float* __restrict__ mask, const float* __restrict__ gamma,
    const float* __restrict__ beta, float* __restrict__ out,
    unsigned short* __restrict__ outb, int m1, int m2) {
  int row = blockIdx.x * 4 + (threadIdx.x >> 6);  // b*Tt + t
  int lane = threadIdx.x & 63;
  float mv = mask[row];
  float f1 = m1 ? mv : 1.f;
  float f2 = m2 ? mv : 1.f;
  size_t base = (size_t)row * Hc;
  float v[6], sum = 0.f, sq = 0.f;
#pragma unroll
  for (int j = 0; j < 6; j++) {
    int idx = lane + 64 * j;
    float a = in1[base + idx] * f1 + in2[base + idx] * f2;
    v[j] = a; sum += a; sq = fmaf(a, a, sq);
  }
#pragma unroll
  for (int off = 32; off >= 1; off >>= 1) {
    sum += __shfl_xor(sum, off, 64);
    sq  += __shfl_xor(sq,  off, 64);
  }
  float m = sum * (1.f / Hc);
  float var = sq * (1.f / Hc) - m * m;
  float rs = rsqrtf(var + 1e-4f);
#pragma unroll
  for (int j = 0; j < 6; j++) {
    int idx = lane + 64 * j;
    float o = (v[j] - m) * rs * gamma[idx] + beta[idx];
    out[base + idx] = o;
    if (outb) outb[base + idx] = bfbits(o * mv);
  }
}

// ---------------- diagnostic ----------------
__global__ void diag_kernel(float* out, float v) {
  if (blockIdx.x == 0 && threadIdx.x == 0) out[0] = v;
}

extern "C" void kernel_launch(void* const* d_in, const int* in_sizes, int n_in,
                              void* d_out, int out_size, void* d_ws, size_t ws_size,
                              hipStream_t stream) {
  const float* x_in  = (const float*)d_in[0];
  const float* xmask = (const float*)d_in[1];
  const float* log_dt = (const float*)d_in[2];
  const float* A_re = (const float*)d_in[3];
  const float* A_im = (const float*)d_in[4];
  const float* C_re = (const float*)d_in[5];
  const float* C_im = (const float*)d_in[6];
  const float* Dv   = (const float*)d_in[7];
  const float* Wout = (const float*)d_in[8];
  const float* bout = (const float*)d_in[9];
  const float* g1   = (const float*)d_in[10];
  const float* be1  = (const float*)d_in[11];
  const float* W1   = (const float*)d_in[12];
  const float* bf1  = (const float*)d_in[13];
  const float* W2   = (const float*)d_in[14];
  const float* bf2  = (const float*)d_in[15];
  const float* g2   = (const float*)d_in[16];
  const float* be2  = (const float*)d_in[17];

  const size_t NXf   = (size_t)Bq * Hc * Tt;          // 12,582,912 floats
  const size_t NP    = (size_t)LYR * Hc * N2;
  const size_t YBFf  = NXf / 2;                       // bf16 (B,T,C) region, float units
  const size_t HBFf  = (size_t)Bq * Tt * HFq / 2;     // 25.17M floats (FFN hidden / scan scratch)
  const size_t WOUTf = (size_t)LYR * TWOH * Hc / 2;
  const size_t W1f   = (size_t)LYR * HFq * Hc / 2;
  const size_t W2f   = (size_t)LYR * Hc * HFq / 2;

  size_t need = 2 * NXf + YBFf + HBFf + WOUTf + W1f + W2f + 6 * NP;
  if (ws_size / 4 < need) {
    diag_kernel<<<1, 64, 0, stream>>>((float*)d_out, 1000.0f + (float)(ws_size >> 20));
    return;
  }

  float* ws = (float*)d_ws;
  float* xT   = ws;                       // (B,T,C) fp32 layer state
  float* tmp  = xT + NXf;                 // fp32: GLU out / FFN2 out; scan overlay: Sraw+Sbf
  float* ybfF = tmp + NXf;                // bf16 (B,T,C): y, then x1*mask
  float* hbfF = ybfF + YBFf;              // FFN hidden bf16; scan overlay: Xbf/Yh/T/M/E
  float* wobF = hbfF + HBFf;
  float* w1bF = wobF + WOUTf;
  float* w2bF = w1bF + W1f;
  float* wre  = w2bF + W2f;
  float* wim  = wre + NP;
  float* cdre = wim + NP;
  float* cdim = cdre + NP;
  float* wSre = cdim + NP;
  float* wSim = wSre + NP;

  unsigned short* ybf = (unsigned short*)ybfF;
  unsigned short* hbf = (unsigned short*)hbfF;
  unsigned short* wob = (unsigned short*)wobF;
  unsigned short* w1b = (unsigned short*)w1bF;
  unsigned short* w2b = (unsigned short*)w2bF;
  float* x1 = (float*)d_out;              // post-LN1 fp32 lives in d_out

  // scan scratch overlays
  const size_t XBFu = (size_t)Hc * BC * CHUNK;        // 12.58M ushorts
  unsigned short* Xbf  = (unsigned short*)hbfF;                 // [384][256][128]
  unsigned short* Yh   = Xbf + XBFu;                            // [384][128][256]
  unsigned short* Ttab = Yh + XBFu;                             // [384][128][128]
  unsigned short* Mtab = Ttab + (size_t)Hc * CHUNK * CHUNK;     // [384][128][64]
  unsigned short* Etab = Mtab + (size_t)Hc * CHUNK * 64;        // [384][64][128]
  float* Sraw = tmp;                                            // [384][256][64] fp32
  unsigned short* Sbf = (unsigned short*)(tmp + (size_t)Hc * BC * 64);  // [384][256][64]

  param_kernel<<<(LYR * Hc * N2 + 255) / 256, 256, 0, stream>>>(
      log_dt, A_re, A_im, C_re, C_im, wre, wim, cdre, cdim, wSre, wSim);
  cvt_bf16_kernel<<<(int)(2 * WOUTf + 1023) / 1024, 256, 0, stream>>>(Wout, wob, (int)(WOUTf / 2));
  cvt_bf16_kernel<<<(int)(2 * W1f + 1023) / 1024, 256, 0, stream>>>(W1, w1b, (int)(W1f / 2));
  cvt_bf16_kernel<<<(int)(2 * W2f + 1023) / 1024, 256, 0, stream>>>(W2, w2b, (int)(W2f / 2));
  transpose_fwd<<<dim3(Tt / 32, Hc / 32, Bq), dim3(32, 8), 0, stream>>>(x_in, xT);

  for (int i = 0; i < LYR; i++) {
    size_t po = (size_t)i * Hc * N2;

    // --- per-layer SSM tables (bf16) ---
    fillT_k<<<Hc, 256, 0, stream>>>(wre + po, wim + po, cdre + po, cdim + po,
                                    Dv + (size_t)i * Hc, Ttab);
    fillM_k<<<(Hc * CHUNK + 255) / 256, 256, 0, stream>>>(wre + po, wim + po,
                                                          cdre + po, cdim + po, Mtab);
    fillE_k<<<(Hc * N2 + 255) / 256, 256, 0, stream>>>(wre + po, wim + po, Etab);

    // --- scan as GEMMs ---
    xprep_k<<<dim3(Tt / 32, Hc / 32, Bq), dim3(32, 8), 0, stream>>>(xT, xmask, Xbf);
    states_gemm<<<dim3(BC / 128, Hc), 256, 0, stream>>>(
        (const __bf16*)Etab, (const __bf16*)Xbf, Sraw);
    prefix_k<<<(Hc * Bq * N2 + 255) / 256, 256, 0, stream>>>(Sraw, Sbf, wSre + po, wSim + po);
    conv_gemm<<<dim3(BC / 128, Hc), 256, 0, stream>>>(
        (const __bf16*)Ttab, (const __bf16*)Mtab, (const __bf16*)Xbf, (const __bf16*)Sbf, Yh);
    ytr_k<<<dim3(CHUNK, BC / 32, Hc / 32), dim3(32, 8), 0, stream>>>(Yh, ybf);

    // --- GLU projection ---
    mfma_gemm<2><<<dim3(Tt / 128, Hc / 128, Bq), 256, 0, stream>>>(
        (const __bf16*)ybf, (const __bf16*)(wob + (size_t)i * TWOH * Hc),
        bout + (size_t)i * TWOH, xmask, tmp, nullptr, Hc, Hc);

    // --- x1 = LN(x*mask + glu) ---
    ln_t<<<(Bq * Tt) / 4, 256, 0, stream>>>(
        xT, tmp, xmask, g1 + (size_t)i * Hc, be1 + (size_t)i * Hc, x1, ybf, 1, 0);

    // --- FFN ---
    mfma_gemm<1><<<dim3(Tt / 128, HFq / 128, Bq), 256, 0, stream>>>(
        (const __bf16*)ybf, (const __bf16*)(w1b + (size_t)i * HFq * Hc),
        bf1 + (size_t)i * HFq, xmask, nullptr, hbf, Hc, HFq);
    mfma_gemm<0><<<dim3(Tt / 128, Hc / 128, Bq), 256, 0, stream>>>(
        (const __bf16*)hbf, (const __bf16*)(w2b + (size_t)i * Hc * HFq),
        bf2 + (size_t)i * Hc, xmask, tmp, nullptr, HFq, Hc);

    // --- x = LN(x1 + f*mask) ---
    ln_t<<<(Bq * Tt) / 4, 256, 0, stream>>>(
        x1, tmp, xmask, g2 + (size_t)i * Hc, be2 + (size_t)i * Hc, xT, nullptr, 0, 1);
  }

  transpose_bwd<<<dim3(Tt / 32, Hc / 32, Bq), dim3(32, 8), 0, stream>>>(xT, xmask, (float*)d_out);
}